// Round 1
// baseline (129.974 us; speedup 1.0000x reference)
//
#include <hip/hip_runtime.h>

#define IMG  4096
#define TILE 64
#define GW   68   // gray tile edge  (TILE + 4)
#define GSTR 68
#define EW   66   // edges tile edge (TILE + 2)
#define ESTR 66

__global__ __launch_bounds__(256, 2)
void harris_fused_kernel(const float* __restrict__ x,
                         float* __restrict__ out_edge,
                         float* __restrict__ out_eig) {
    __shared__ float  s_gray[GW * GSTR];        // 18,496 B
    __shared__ float2 s_edge[EW * ESTR];        // 34,848 B  (total 53,344 B -> 3 blocks/CU)

    const int tid = threadIdx.x;
    const int bx = blockIdx.x, by = blockIdx.y;
    const int gx0 = bx * TILE - 2;              // global col of gray-tile origin
    const int gy0 = by * TILE - 2;              // global row of gray-tile origin

    const float* __restrict__ x0 = x;
    const float* __restrict__ x1 = x + (size_t)IMG * IMG;
    const float* __restrict__ x2 = x + 2 * (size_t)IMG * IMG;

    // ---------------- Phase 1: gray = 0.299 R + 0.587 G + 0.114 B, zero-padded ----------------
    #pragma unroll 4
    for (int k = 0; k < (GW * GW + 255) / 256; ++k) {
        int idx = tid + k * 256;
        if (idx < GW * GW) {
            int r = idx / GW, c = idx - r * GW;
            int gy = gy0 + r, gx = gx0 + c;
            float g = 0.0f;
            if ((unsigned)gy < (unsigned)IMG && (unsigned)gx < (unsigned)IMG) {
                int off = gy * IMG + gx;
                g = 0.299f * x0[off] + 0.587f * x1[off] + 0.114f * x2[off];
            }
            s_gray[r * GSTR + c] = g;
        }
    }
    __syncthreads();

    // ---------------- Phase 2: Scharr edges (cross-correlation, zero outside image) ----------
    // Ix kernel: [[-3,0,3],[-10,0,10],[-3,0,3]]   Iy kernel: transpose
    #pragma unroll 4
    for (int k = 0; k < (EW * EW + 255) / 256; ++k) {
        int idx = tid + k * 256;
        if (idx < EW * EW) {
            int r = idx / EW, c = idx - r * EW;
            int gy = gy0 + 1 + r, gx = gx0 + 1 + c;   // global position of this edge pixel
            float ix = 0.0f, iy = 0.0f;
            if ((unsigned)gy < (unsigned)IMG && (unsigned)gx < (unsigned)IMG) {
                const float* g = &s_gray[r * GSTR + c];
                float a  = g[0];            float b  = g[1];            float cc = g[2];
                float d  = g[GSTR];                                     float f  = g[GSTR + 2];
                float h  = g[2 * GSTR];     float i2 = g[2 * GSTR + 1]; float j  = g[2 * GSTR + 2];
                ix = 3.0f * (cc - a) + 10.0f * (f - d)  + 3.0f * (j - h);
                iy = 3.0f * (h - a)  + 10.0f * (i2 - b) + 3.0f * (j - cc);
            }
            s_edge[r * ESTR + c] = make_float2(ix, iy);
        }
    }
    __syncthreads();

    // ---------------- Phase 3: box(3x3) of {Ix^2, Iy^2, IxIy} + epilogues, 4x4 per thread ----
    const int tx = tid & 15, ty = tid >> 4;
    const int c0 = tx * 4, r0 = ty * 4;                // micro-tile origin within 64x64 tile
    const int h0 = by * TILE + r0, w0 = bx * TILE + c0;

    #pragma unroll
    for (int i = 0; i < 4; ++i) {
        const int r = r0 + i;                           // edges-local top row of 3x3 window
        float cxx[6], cyy[6], cxy[6], cx[6], cy[6];
        #pragma unroll
        for (int j = 0; j < 6; ++j) {
            float2 e0 = s_edge[(r    ) * ESTR + c0 + j];
            float2 e1 = s_edge[(r + 1) * ESTR + c0 + j];
            float2 e2 = s_edge[(r + 2) * ESTR + c0 + j];
            cxx[j] = e0.x * e0.x + e1.x * e1.x + e2.x * e2.x;
            cyy[j] = e0.y * e0.y + e1.y * e1.y + e2.y * e2.y;
            cxy[j] = e0.x * e0.y + e1.x * e1.y + e2.x * e2.y;
            cx[j]  = e1.x;                              // center row (for edge magnitude)
            cy[j]  = e1.y;
        }
        float4 edge_v, eig_v;
        float* ep = &edge_v.x;
        float* vp = &eig_v.x;
        #pragma unroll
        for (int jj = 0; jj < 4; ++jj) {
            float sxx = cxx[jj] + cxx[jj + 1] + cxx[jj + 2];
            float syy = cyy[jj] + cyy[jj + 1] + cyy[jj + 2];
            float sxy = cxy[jj] + cxy[jj + 1] + cxy[jj + 2];
            float diff = sxx - syy;
            float tr   = sxx + syy;
            vp[jj] = tr - sqrtf(diff * diff + 4.0f * sxy * sxy);
            ep[jj] = 0.5f * (fabsf(cx[jj + 1]) + fabsf(cy[jj + 1]));
        }
        const int off = (h0 + i) * IMG + w0;            // w0 % 4 == 0 -> 16B-aligned
        *reinterpret_cast<float4*>(&out_edge[off]) = edge_v;
        *reinterpret_cast<float4*>(&out_eig [off]) = eig_v;
    }
}

extern "C" void kernel_launch(void* const* d_in, const int* in_sizes, int n_in,
                              void* d_out, int out_size, void* d_ws, size_t ws_size,
                              hipStream_t stream) {
    const float* x = (const float*)d_in[0];
    float* out      = (float*)d_out;
    float* out_edge = out;                       // output 0: (1,4096,4096)
    float* out_eig  = out + (size_t)IMG * IMG;   // output 1: (1,4096,4096)

    dim3 grid(IMG / TILE, IMG / TILE);
    harris_fused_kernel<<<grid, dim3(256), 0, stream>>>(x, out_edge, out_eig);
}

// Round 2
// 103.542 us; speedup vs baseline: 1.2553x; 1.2553x over previous
//
#include <hip/hip_runtime.h>

#define IMG   4096
#define TILE  64
#define GDIM  68            // gray tile edge (TILE + 4)
#define GSTR  68            // gray stride (floats)
#define EROWS 66            // edge rows (TILE + 2)
#define ESTR  67            // edge stride in float2 (odd -> breaks bank aliasing)
#define NPAIR (EROWS * 33)  // 2178 edge-pairs per tile

__global__ __launch_bounds__(512, 6)
void harris_fused_kernel(const float* __restrict__ x,
                         float* __restrict__ out_edge,
                         float* __restrict__ out_eig) {
    __shared__ float  s_gray[GDIM * GSTR];    // 18,496 B
    __shared__ float2 s_edge[EROWS * ESTR];   // 35,376 B  (total 53,872 -> 3 blocks/CU)

    const int tid = threadIdx.x;
    const int bx = blockIdx.x, by = blockIdx.y;
    const int gx0 = bx * TILE - 2;
    const int gy0 = by * TILE - 2;
    const bool interior = (bx > 0) && (bx < IMG / TILE - 1) && (by > 0) && (by < IMG / TILE - 1);

    const float* __restrict__ x0 = x;
    const float* __restrict__ x1 = x + (size_t)IMG * IMG;
    const float* __restrict__ x2 = x + 2 * (size_t)IMG * IMG;

    // ---------------- Phase 1: gray = 0.299 R + 0.587 G + 0.114 B (zero-padded halo) -------
    if (interior) {
        #pragma unroll
        for (int k = 0; k < 10; ++k) {
            int idx = tid + k * 512;
            if (idx < GDIM * GDIM) {
                int r = (int)((unsigned)idx / (unsigned)GDIM);
                int c = idx - r * GDIM;
                int off = (gy0 + r) * IMG + (gx0 + c);
                s_gray[r * GSTR + c] = 0.299f * x0[off] + 0.587f * x1[off] + 0.114f * x2[off];
            }
        }
    } else {
        #pragma unroll
        for (int k = 0; k < 10; ++k) {
            int idx = tid + k * 512;
            if (idx < GDIM * GDIM) {
                int r = (int)((unsigned)idx / (unsigned)GDIM);
                int c = idx - r * GDIM;
                int gy = gy0 + r, gx = gx0 + c;
                float g = 0.0f;
                if ((unsigned)gy < (unsigned)IMG && (unsigned)gx < (unsigned)IMG) {
                    int off = gy * IMG + gx;
                    g = 0.299f * x0[off] + 0.587f * x1[off] + 0.114f * x2[off];
                }
                s_gray[r * GSTR + c] = g;
            }
        }
    }
    __syncthreads();

    // ---------------- Phase 2: Scharr edges, two adjacent columns per thread ----------------
    // pair p: row er = p/33, t = p%33 -> edge cols (2t+1, 2t+2) of [0..66], rows 0..65
    #pragma unroll
    for (int k = 0; k < 5; ++k) {
        int p = tid + k * 512;
        if (p < NPAIR) {
            int er = (int)((unsigned)p / 33u);
            int t  = p - er * 33;
            const float* g = &s_gray[er * GSTR + 2 * t];
            float2 g0a = *(const float2*)(g);
            float2 g0b = *(const float2*)(g + 2);
            float2 g1a = *(const float2*)(g + GSTR);
            float2 g1b = *(const float2*)(g + GSTR + 2);
            float2 g2a = *(const float2*)(g + 2 * GSTR);
            float2 g2b = *(const float2*)(g + 2 * GSTR + 2);
            // edge col 2t+1 : gray cols (2t)=a.x (2t+1)=a.y (2t+2)=b.x
            float ix1 = 3.0f * (g0b.x - g0a.x) + 10.0f * (g1b.x - g1a.x) + 3.0f * (g2b.x - g2a.x);
            float iy1 = 3.0f * (g2a.x - g0a.x) + 10.0f * (g2a.y - g0a.y) + 3.0f * (g2b.x - g0b.x);
            // edge col 2t+2 : gray cols (2t+1)=a.y (2t+2)=b.x (2t+3)=b.y
            float ix2 = 3.0f * (g0b.y - g0a.y) + 10.0f * (g1b.y - g1a.y) + 3.0f * (g2b.y - g2a.y);
            float iy2 = 3.0f * (g2a.y - g0a.y) + 10.0f * (g2b.x - g0b.x) + 3.0f * (g2b.y - g0b.y);
            if (!interior) {
                int gy  = by * TILE - 1 + er;
                int gxA = bx * TILE - 1 + 2 * t;
                int gxB = gxA + 1;
                bool okY = (unsigned)gy < (unsigned)IMG;
                if (!(okY && (unsigned)gxA < (unsigned)IMG)) { ix1 = 0.0f; iy1 = 0.0f; }
                if (!(okY && (unsigned)gxB < (unsigned)IMG)) { ix2 = 0.0f; iy2 = 0.0f; }
            }
            s_edge[er * ESTR + 2 * t + 1] = make_float2(ix1, iy1);
            s_edge[er * ESTR + 2 * t + 2] = make_float2(ix2, iy2);
        }
    }
    __syncthreads();

    // ---------------- Phase 3: 3x3 box of products + epilogues, 1 row x 8 cols per thread ---
    const int tx8 = tid & 7;
    const int v   = tid >> 3;        // output row within tile (0..63)
    const int c0  = tx8 * 8;         // output col base within tile

    float axx[10], ayy[10], axy[10];
    #pragma unroll
    for (int j = 0; j < 10; ++j) { axx[j] = 0.0f; ayy[j] = 0.0f; axy[j] = 0.0f; }
    float edge_mag[8];

    #pragma unroll
    for (int rr = 0; rr < 3; ++rr) {
        const float2* e = &s_edge[(v + rr) * ESTR + c0 + 1];
        float2 ev[10];
        #pragma unroll
        for (int j = 0; j < 10; ++j) ev[j] = e[j];
        #pragma unroll
        for (int j = 0; j < 10; ++j) {
            axx[j] += ev[j].x * ev[j].x;
            ayy[j] += ev[j].y * ev[j].y;
            axy[j] += ev[j].x * ev[j].y;
        }
        if (rr == 1) {
            #pragma unroll
            for (int q = 0; q < 8; ++q)
                edge_mag[q] = 0.5f * (fabsf(ev[q + 1].x) + fabsf(ev[q + 1].y));
        }
    }

    float4 eg0, eg1, ei0, ei1;
    float* egp0 = &eg0.x; float* egp1 = &eg1.x;
    float* eip0 = &ei0.x; float* eip1 = &ei1.x;
    #pragma unroll
    for (int q = 0; q < 8; ++q) {
        float sxx = axx[q] + axx[q + 1] + axx[q + 2];
        float syy = ayy[q] + ayy[q + 1] + ayy[q + 2];
        float sxy = axy[q] + axy[q + 1] + axy[q + 2];
        float diff = sxx - syy;
        float tr   = sxx + syy;
        float eig  = tr - sqrtf(diff * diff + 4.0f * sxy * sxy);
        if (q < 4) { egp0[q] = edge_mag[q]; eip0[q] = eig; }
        else       { egp1[q - 4] = edge_mag[q]; eip1[q - 4] = eig; }
    }
    const int h  = by * TILE + v;
    const int w0 = bx * TILE + c0;
    const int off = h * IMG + w0;
    *reinterpret_cast<float4*>(&out_edge[off])     = eg0;
    *reinterpret_cast<float4*>(&out_edge[off + 4]) = eg1;
    *reinterpret_cast<float4*>(&out_eig [off])     = ei0;
    *reinterpret_cast<float4*>(&out_eig [off + 4]) = ei1;
}

extern "C" void kernel_launch(void* const* d_in, const int* in_sizes, int n_in,
                              void* d_out, int out_size, void* d_ws, size_t ws_size,
                              hipStream_t stream) {
    const float* x = (const float*)d_in[0];
    float* out      = (float*)d_out;
    float* out_edge = out;                       // output 0: (1,4096,4096)
    float* out_eig  = out + (size_t)IMG * IMG;   // output 1: (1,4096,4096)

    dim3 grid(IMG / TILE, IMG / TILE);
    harris_fused_kernel<<<grid, dim3(512), 0, stream>>>(x, out_edge, out_eig);
}

// Round 4
// 89.963 us; speedup vs baseline: 1.4447x; 1.1509x over previous
//
#include <hip/hip_runtime.h>

#define IMG   4096
#define TW    64             // tile width
#define TH    32             // tile height
#define GR    36             // gray rows  (TH + 4)
#define GC    68             // gray cols  (TW + 4)  -> 272 B row stride, 16B-aligned
#define NBX   (IMG / TW)     // 64
#define NBY   (IMG / TH)     // 128
#define GN    (GR * GC)      // 2448 floats = 9792 B LDS
#define W103  3.33333333333333f   // 10/3 (x3 scharr scale deferred to epilogue)

typedef float f32x4 __attribute__((ext_vector_type(4)));

__global__ __launch_bounds__(256, 4)
void harris_fused(const float* __restrict__ x,
                  float* __restrict__ out_edge,
                  float* __restrict__ out_eig)
{
    __shared__ float s_gray[GN];

    const int tid = threadIdx.x;
    const int bx = blockIdx.x, by = blockIdx.y;
    const int H0  = by * TH;
    const int W0b = bx * TW;
    const int gx0 = W0b - 2;
    const int gy0 = H0  - 2;
    const bool interior = (bx > 0) && (bx < NBX - 1) && (by > 0) && (by < NBY - 1);

    const float* __restrict__ x0 = x;
    const float* __restrict__ x1 = x + (size_t)IMG * IMG;
    const float* __restrict__ x2 = x + 2 * (size_t)IMG * IMG;

    // ---------------- Phase 1: gray into LDS (zero-padded halo), one barrier total --------
    if (interior) {
        #pragma unroll
        for (int k = 0; k < 9; ++k) {                 // idx <= 2303 < 2448, no check needed
            int idx = tid + k * 256;
            int r = (int)((unsigned)idx / (unsigned)GC);
            int c = idx - r * GC;
            int off = (gy0 + r) * IMG + (gx0 + c);
            s_gray[idx] = 0.299f * x0[off] + 0.587f * x1[off] + 0.114f * x2[off];
        }
        {   int idx = tid + 9 * 256;                  // tail: 144 active
            if (idx < GN) {
                int r = (int)((unsigned)idx / (unsigned)GC);
                int c = idx - r * GC;
                int off = (gy0 + r) * IMG + (gx0 + c);
                s_gray[idx] = 0.299f * x0[off] + 0.587f * x1[off] + 0.114f * x2[off];
            }
        }
    } else {
        #pragma unroll
        for (int k = 0; k < 10; ++k) {
            int idx = tid + k * 256;
            if (idx < GN) {
                int r = (int)((unsigned)idx / (unsigned)GC);
                int c = idx - r * GC;
                int gy = gy0 + r, gx = gx0 + c;
                float g = 0.0f;
                if ((unsigned)gy < (unsigned)IMG && (unsigned)gx < (unsigned)IMG) {
                    int off = gy * IMG + gx;
                    g = 0.299f * x0[off] + 0.587f * x1[off] + 0.114f * x2[off];
                }
                s_gray[idx] = g;
            }
        }
    }
    __syncthreads();

    // ---------------- Phase 2: separable Scharr + box + epilogues, 1 row x 8 cols/thread --
    const int tx = tid & 7;          // 0..7  -> col group
    const int v  = tid >> 3;         // 0..31 -> output row within tile
    const int c0 = tx * 8;           // gray-local col base (16B aligned)

    float ga[12], gb[12], gc_[12];
    float axx[10], ayy[10], axy[10];
    #pragma unroll
    for (int e = 0; e < 10; ++e) { axx[e] = 0.f; ayy[e] = 0.f; axy[e] = 0.f; }

    auto loadrow = [&](float* dst, int l) {
        const float4* p = reinterpret_cast<const float4*>(&s_gray[(v + l) * GC + c0]);
        float4 t0 = p[0], t1 = p[1], t2 = p[2];
        dst[0] = t0.x; dst[1] = t0.y; dst[2]  = t0.z; dst[3]  = t0.w;
        dst[4] = t1.x; dst[5] = t1.y; dst[6]  = t1.z; dst[7]  = t1.w;
        dst[8] = t2.x; dst[9] = t2.y; dst[10] = t2.z; dst[11] = t2.w;
    };

    auto contrib = [&](const float* top, const float* mid, const float* bot, int K) {
        float s[12], d[12];
        #pragma unroll
        for (int j = 0; j < 12; ++j) {
            s[j] = (top[j] + bot[j]) + W103 * mid[j];   // vertical smooth (/3)
            d[j] = bot[j] - top[j];                      // vertical diff
        }
        float ix[10], iy[10];
        #pragma unroll
        for (int e = 0; e < 10; ++e) {
            ix[e] = s[e + 2] - s[e];                               // Ix/3
            iy[e] = (d[e] + d[e + 2]) + W103 * d[e + 1];           // Iy/3
        }
        if (!interior) {   // zero edges outside the image (box conv zero-pads edges)
            if (bx == 0       && tx == 0) { ix[0] = 0.f; iy[0] = 0.f; }
            if (bx == NBX - 1 && tx == 7) { ix[9] = 0.f; iy[9] = 0.f; }
        }
        bool row_ok = true;
        if (K == 0 && by == 0       && v == 0)      row_ok = false;  // edge row -1
        if (K == 2 && by == NBY - 1 && v == TH - 1) row_ok = false;  // edge row 4096
        if (row_ok) {
            #pragma unroll
            for (int e = 0; e < 10; ++e) {
                axx[e] += ix[e] * ix[e];
                ayy[e] += iy[e] * iy[e];
                axy[e] += ix[e] * iy[e];
            }
        }
        if (K == 1) {      // center row: edge magnitude = (|Ix|+|Iy|)/2 = 1.5*(|ix'|+|iy'|)
            f32x4 m0, m1;
            m0.x = 1.5f * (fabsf(ix[1]) + fabsf(iy[1]));
            m0.y = 1.5f * (fabsf(ix[2]) + fabsf(iy[2]));
            m0.z = 1.5f * (fabsf(ix[3]) + fabsf(iy[3]));
            m0.w = 1.5f * (fabsf(ix[4]) + fabsf(iy[4]));
            m1.x = 1.5f * (fabsf(ix[5]) + fabsf(iy[5]));
            m1.y = 1.5f * (fabsf(ix[6]) + fabsf(iy[6]));
            m1.z = 1.5f * (fabsf(ix[7]) + fabsf(iy[7]));
            m1.w = 1.5f * (fabsf(ix[8]) + fabsf(iy[8]));
            const int off = (H0 + v) * IMG + W0b + c0;
            __builtin_nontemporal_store(m0, reinterpret_cast<f32x4*>(&out_edge[off]));
            __builtin_nontemporal_store(m1, reinterpret_cast<f32x4*>(&out_edge[off + 4]));
        }
    };

    loadrow(ga, 0); loadrow(gb, 1); loadrow(gc_, 2);
    contrib(ga, gb, gc_, 0);
    loadrow(ga, 3);
    contrib(gb, gc_, ga, 1);
    loadrow(gb, 4);
    contrib(gc_, ga, gb, 2);

    f32x4 e0, e1;
    #pragma unroll
    for (int q = 0; q < 8; ++q) {
        float sxx = axx[q] + axx[q + 1] + axx[q + 2];
        float syy = ayy[q] + ayy[q + 1] + ayy[q + 2];
        float sxy = axy[q] + axy[q + 1] + axy[q + 2];
        float diff = sxx - syy;
        float tr   = sxx + syy;
        float val  = 9.0f * (tr - sqrtf(diff * diff + 4.0f * sxy * sxy));
        if (q < 4) e0[q] = val; else e1[q - 4] = val;
    }
    const int off = (H0 + v) * IMG + W0b + c0;
    __builtin_nontemporal_store(e0, reinterpret_cast<f32x4*>(&out_eig[off]));
    __builtin_nontemporal_store(e1, reinterpret_cast<f32x4*>(&out_eig[off + 4]));
}

extern "C" void kernel_launch(void* const* d_in, const int* in_sizes, int n_in,
                              void* d_out, int out_size, void* d_ws, size_t ws_size,
                              hipStream_t stream) {
    const float* x = (const float*)d_in[0];
    float* out      = (float*)d_out;
    float* out_edge = out;                       // output 0: (1,4096,4096)
    float* out_eig  = out + (size_t)IMG * IMG;   // output 1: (1,4096,4096)

    dim3 grid(NBX, NBY);
    harris_fused<<<grid, dim3(256), 0, stream>>>(x, out_edge, out_eig);
}